// Round 16
// baseline (111.783 us; speedup 1.0000x reference)
//
#include <hip/hip_runtime.h>
#include <hip/hip_bf16.h>

#define NNODES 100000
#define NEDGES 1600000
#define IN_C   256
#define OUT_C  128

typedef short bf16x8 __attribute__((ext_vector_type(8)));
typedef float f32x4  __attribute__((ext_vector_type(4)));
typedef unsigned int u32x2 __attribute__((ext_vector_type(2)));

static __device__ __forceinline__ unsigned short f2bf(float f) {
    union { float f; unsigned u; } c; c.f = f;
    unsigned r = c.u + 0x7fffu + ((c.u >> 16) & 1u);   // round-to-nearest-even
    return (unsigned short)(r >> 16);
}

union BF8 { bf16x8 v; unsigned short s[8]; };

// ---------------------------------------------------------------------------
// GEMM: H8(biased uint8, row-major, per-row scale) = quant(X @ W^T).
// (R12-exact: W in 64KB swizzled LDS, X direct to A-frags, barrier-free
//  K-loop, per-row amax -> q+128 uint8.)
// ---------------------------------------------------------------------------
__global__ __launch_bounds__(512, 4) void gemm_xwt(const float* __restrict__ X,
                                                   const float* __restrict__ W,
                                                   unsigned char* __restrict__ H8,
                                                   float* __restrict__ scale) {
    __shared__ unsigned short Wsh[128 * 256];   // bf16 bits, [n][k], swizzled, 64KB

    const int tid  = threadIdx.x;
    const int lane = tid & 63;
    const int wid  = tid >> 6;                  // 0..7

#pragma unroll
    for (int p = 0; p < 16; ++p) {
        int idx = p * 512 + tid;                // 0..8191 float4 index
        int n   = idx >> 6;                     // 0..127
        int c4  = idx & 63;                     // float4 column
        float4 v = *(const float4*)(W + (size_t)n * IN_C + c4 * 4);
        int byte = (n * 512 + c4 * 8) ^ ((n & 7) << 4);
        *(ushort4*)((char*)Wsh + byte) =
            make_ushort4(f2bf(v.x), f2bf(v.y), f2bf(v.z), f2bf(v.w));
    }
    __syncthreads();

    const int r0   = blockIdx.x * 128 + wid * 16;
    int arow = r0 + (lane & 15);
    if (arow > NNODES - 1) arow = NNODES - 1;   // clamp (tail rows discarded)
    const float* xrow = X + (size_t)arow * IN_C + (lane >> 4) * 8;

    f32x4 acc[8] = {};
#pragma unroll
    for (int ks = 0; ks < 8; ++ks) {
        float4 a0 = *(const float4*)(xrow + ks * 32);
        float4 a1 = *(const float4*)(xrow + ks * 32 + 4);
        BF8 t;
        t.s[0] = f2bf(a0.x); t.s[1] = f2bf(a0.y); t.s[2] = f2bf(a0.z); t.s[3] = f2bf(a0.w);
        t.s[4] = f2bf(a1.x); t.s[5] = f2bf(a1.y); t.s[6] = f2bf(a1.z); t.s[7] = f2bf(a1.w);
        const int kb = ks * 64 + (lane >> 4) * 16;      // byte offset in W row
#pragma unroll
        for (int n8 = 0; n8 < 8; ++n8) {
            int nr   = n8 * 16 + (lane & 15);
            int byte = (nr * 512 + kb) ^ ((nr & 7) << 4);
            bf16x8 b = *(const bf16x8*)((const char*)Wsh + byte);
            acc[n8] = __builtin_amdgcn_mfma_f32_16x16x32_bf16(t.v, b, acc[n8],
                                                              0, 0, 0);
        }
    }

    // --- epilogue: per-row amax -> biased-uint8 quantize (row-major) ---
    float amax[4];
#pragma unroll
    for (int r = 0; r < 4; ++r) {
        float m = 0.f;
#pragma unroll
        for (int n8 = 0; n8 < 8; ++n8) m = fmaxf(m, fabsf(acc[n8][r]));
        amax[r] = m;
    }
#pragma unroll
    for (int d = 1; d < 16; d <<= 1)
#pragma unroll
        for (int r = 0; r < 4; ++r)
            amax[r] = fmaxf(amax[r], __shfl_xor(amax[r], d));

#pragma unroll
    for (int r = 0; r < 4; ++r) {
        int grow = r0 + (lane >> 4) * 4 + r;
        if (grow < NNODES) {
            float am  = amax[r];
            float inv = am > 0.f ? 127.f / am : 0.f;
            if ((lane & 15) == 0) scale[grow] = am * (1.f / 127.f);
#pragma unroll
            for (int n8 = 0; n8 < 8; ++n8) {
                float q = rintf(acc[n8][r] * inv);
                q = fminf(127.f, fmaxf(-127.f, q));
                H8[(size_t)grow * OUT_C + n8 * 16 + (lane & 15)] =
                    (unsigned char)((int)q + 128);
            }
        }
    }
}

// ---------------------------------------------------------------------------
// rowptr[r] = lower_bound(A_rows, r)  (A_rows sorted).  r in [0, N].
// ---------------------------------------------------------------------------
__global__ __launch_bounds__(256) void build_rowptr(const int* __restrict__ rows,
                                                    int* __restrict__ rowptr) {
    int r = blockIdx.x * 256 + threadIdx.x;
    if (r > NNODES) return;
    int lo = 0, hi = NEDGES;
    while (lo < hi) {
        int mid = (lo + hi) >> 1;
        if (rows[mid] < r) lo = mid + 1; else hi = mid;
    }
    rowptr[r] = lo;
}

// ---------------------------------------------------------------------------
// SpMM: out[r,:] = sum_e vals[e]*scale[c_e] * H8[c_e,:].
// R10-exact inner structure (2-row pipeline, 64-edge shfl preload, interleaved
// edge4 calls, wave-uniform guards) with TWO new levers:
//  (1) PERSISTENT GRID-STRIDE: 2048 blocks; each wave loops ~6 row-pairs ->
//      launch/drain amortized, gather pipeline stays warm.
//  (2) NT (L1-bypass) H gathers: H lines have ~0.25% L1 hit probability;
//      bypassing L1 attacks the ~26-outstanding-miss/CU cap.
// Biased-uint8 unpack + exact -128*sum(w) correction. NT out stores.
// ---------------------------------------------------------------------------
#define SPMM_BLOCKS 2048

static __device__ __forceinline__ void edge4nt(float acc[8], float* sw,
                                               int ec, float ev, int jg,
                                               const u32x2* __restrict__ H2,
                                               int cg) {
    int   c = __shfl(ec, jg);
    float v = __shfl(ev, jg);
    u32x2 u = __builtin_nontemporal_load(H2 + (size_t)c * 16 + cg);
    *sw += v;
    acc[0] += v * (float)( u[0]        & 0xffu);
    acc[1] += v * (float)((u[0] >>  8) & 0xffu);
    acc[2] += v * (float)((u[0] >> 16) & 0xffu);
    acc[3] += v * (float)( u[0] >> 24);
    acc[4] += v * (float)( u[1]        & 0xffu);
    acc[5] += v * (float)((u[1] >>  8) & 0xffu);
    acc[6] += v * (float)((u[1] >> 16) & 0xffu);
    acc[7] += v * (float)( u[1] >> 24);
}

__global__ __launch_bounds__(256) void spmm_rows(const u32x2* __restrict__ H2,
                                                 const int* __restrict__ rowptr,
                                                 const int* __restrict__ cols,
                                                 const float* __restrict__ vals,
                                                 const float* __restrict__ scale,
                                                 float* __restrict__ out) {
    const int wid  = threadIdx.x >> 6;
    const int lane = threadIdx.x & 63;
    const int g    = lane >> 4;      // edge subgroup 0..3
    const int cg   = lane & 15;      // channel group: channels cg*8 .. cg*8+7

    for (int pair = blockIdx.x * 4 + wid; pair < NNODES / 2;
         pair += SPMM_BLOCKS * 4) {
        const int rowA = pair * 2;               // rowB = rowA + 1
        const int sA = rowptr[rowA];
        const int eA = rowptr[rowA + 1];
        const int eB = rowptr[rowA + 2];

        float accA[8], accB[8];
#pragma unroll
        for (int t = 0; t < 8; ++t) { accA[t] = 0.f; accB[t] = 0.f; }
        float swA = 0.f, swB = 0.f;

        int baseA = sA, baseB = eA;
        while (baseA < eA || baseB < eB) {
            int cntA = eA - baseA; cntA = cntA < 0 ? 0 : (cntA > 64 ? 64 : cntA);
            int cntB = eB - baseB; cntB = cntB < 0 ? 0 : (cntB > 64 ? 64 : cntB);

            int   ecA = 0, ecB = 0;
            float evA = 0.f, evB = 0.f;
            if (lane < cntA) { ecA = cols[baseA + lane];
                               evA = vals[baseA + lane] * scale[ecA]; }
            if (lane < cntB) { ecB = cols[baseB + lane];
                               evB = vals[baseB + lane] * scale[ecB]; }

            const int mx = cntA > cntB ? cntA : cntB;
            for (int j = 0; j < mx; j += 8) {
                if (j < cntA)     edge4nt(accA, &swA, ecA, evA, j + g,     H2, cg);
                if (j < cntB)     edge4nt(accB, &swB, ecB, evB, j + g,     H2, cg);
                if (j + 4 < cntA) edge4nt(accA, &swA, ecA, evA, j + 4 + g, H2, cg);
                if (j + 4 < cntB) edge4nt(accB, &swB, ecB, evB, j + 4 + g, H2, cg);
            }

            baseA += cntA;
            baseB += cntB;
        }

        // reduce across the 4 edge subgroups, then exact bias correction
#pragma unroll
        for (int t = 0; t < 8; ++t) {
            accA[t] += __shfl_xor(accA[t], 16);
            accA[t] += __shfl_xor(accA[t], 32);
            accB[t] += __shfl_xor(accB[t], 16);
            accB[t] += __shfl_xor(accB[t], 32);
        }
        swA += __shfl_xor(swA, 16); swA += __shfl_xor(swA, 32);
        swB += __shfl_xor(swB, 16); swB += __shfl_xor(swB, 32);

        if (lane < 16) {
            const float bA = 128.f * swA, bB = 128.f * swB;
            f32x4 a0 = { accA[0] - bA, accA[1] - bA, accA[2] - bA, accA[3] - bA };
            f32x4 a1 = { accA[4] - bA, accA[5] - bA, accA[6] - bA, accA[7] - bA };
            f32x4 b0 = { accB[0] - bB, accB[1] - bB, accB[2] - bB, accB[3] - bB };
            f32x4 b1 = { accB[4] - bB, accB[5] - bB, accB[6] - bB, accB[7] - bB };
            __builtin_nontemporal_store(a0, (f32x4*)(out + (size_t)rowA * OUT_C + cg * 8));
            __builtin_nontemporal_store(a1, (f32x4*)(out + (size_t)rowA * OUT_C + cg * 8 + 4));
            __builtin_nontemporal_store(b0, (f32x4*)(out + (size_t)(rowA + 1) * OUT_C + cg * 8));
            __builtin_nontemporal_store(b1, (f32x4*)(out + (size_t)(rowA + 1) * OUT_C + cg * 8 + 4));
        }
    }
}

// ---------------------------------------------------------------------------
extern "C" void kernel_launch(void* const* d_in, const int* in_sizes, int n_in,
                              void* d_out, int out_size, void* d_ws, size_t ws_size,
                              hipStream_t stream) {
    const float* X      = (const float*)d_in[0];
    const float* W      = (const float*)d_in[1];
    const int*   A_rows = (const int*)d_in[2];
    const int*   A_cols = (const int*)d_in[3];
    const float* A_vals = (const float*)d_in[4];
    float* out = (float*)d_out;

    unsigned char* H8     = (unsigned char*)d_ws;                          // 12.8 MB
    float*         scale  = (float*)((char*)d_ws + (size_t)NNODES * OUT_C); // 400 KB
    int*           rowptr = (int*)((char*)scale + (size_t)NNODES * sizeof(float));

    gemm_xwt<<<(NNODES + 127) / 128, 512, 0, stream>>>(X, W, H8, scale);
    build_rowptr<<<(NNODES + 1 + 255) / 256, 256, 0, stream>>>(A_rows, rowptr);
    spmm_rows<<<SPMM_BLOCKS, 256, 0, stream>>>((const u32x2*)H8, rowptr,
                                               A_cols, A_vals, scale, out);
}

// Round 17
// 94.057 us; speedup vs baseline: 1.1885x; 1.1885x over previous
//
#include <hip/hip_runtime.h>
#include <hip/hip_bf16.h>

#define NNODES 100000
#define NEDGES 1600000
#define IN_C   256
#define OUT_C  128

typedef short bf16x8 __attribute__((ext_vector_type(8)));
typedef float f32x4  __attribute__((ext_vector_type(4)));

static __device__ __forceinline__ unsigned short f2bf(float f) {
    union { float f; unsigned u; } c; c.f = f;
    unsigned r = c.u + 0x7fffu + ((c.u >> 16) & 1u);   // round-to-nearest-even
    return (unsigned short)(r >> 16);
}

// ---------------------------------------------------------------------------
// One-time W pre-convert: f32 [128][256] -> bf16, XOR-swizzled layout
// (byte = (n*512 + c4*8) ^ ((n&7)<<4)) so gemm staging is a linear copy.
// ---------------------------------------------------------------------------
__global__ __launch_bounds__(256) void wprep(const float* __restrict__ W,
                                             unsigned short* __restrict__ Wbf) {
    int idx = blockIdx.x * 256 + threadIdx.x;   // 0..8191 float4 index
    int n   = idx >> 6;                         // 0..127
    int c4  = idx & 63;                         // float4 column
    float4 v = *(const float4*)(W + (size_t)n * IN_C + c4 * 4);
    int byte = (n * 512 + c4 * 8) ^ ((n & 7) << 4);
    *(ushort4*)((char*)Wbf + byte) =
        make_ushort4(f2bf(v.x), f2bf(v.y), f2bf(v.z), f2bf(v.w));
}

// ---------------------------------------------------------------------------
// GEMM: H8(int8, per-row scale) = quant(X @ W^T).  (R10 structure; staging
// now a linear 64KB copy of the pre-swizzled bf16 W — no converts, no f32.)
// ---------------------------------------------------------------------------
__global__ __launch_bounds__(512, 4) void gemm_xwt(const float* __restrict__ X,
                                                   const unsigned short* __restrict__ Wbf,
                                                   signed char* __restrict__ H8,
                                                   float* __restrict__ scale) {
    __shared__ unsigned short Wsh[128 * 256];   // bf16 bits, swizzled, 64KB

    const int tid  = threadIdx.x;
    const int lane = tid & 63;
    const int wid  = tid >> 6;                  // 0..7

    // stage W: linear 64KB copy (swizzle baked into Wbf)
    const uint4* Wsrc = (const uint4*)Wbf;
#pragma unroll
    for (int p = 0; p < 8; ++p) {
        int i = p * 512 + tid;                  // 0..4095 x 16B
        ((uint4*)Wsh)[i] = Wsrc[i];
    }
    __syncthreads();

    const int r0   = blockIdx.x * 128 + wid * 16;
    int arow = r0 + (lane & 15);
    if (arow > NNODES - 1) arow = NNODES - 1;   // clamp (tail rows discarded)
    const float* xrow = X + (size_t)arow * IN_C + (lane >> 4) * 8;

    f32x4 acc[8] = {};
#pragma unroll
    for (int ks = 0; ks < 8; ++ks) {
        float4 a0 = *(const float4*)(xrow + ks * 32);
        float4 a1 = *(const float4*)(xrow + ks * 32 + 4);
        union { bf16x8 v; unsigned short s[8]; } t;
        t.s[0] = f2bf(a0.x); t.s[1] = f2bf(a0.y); t.s[2] = f2bf(a0.z); t.s[3] = f2bf(a0.w);
        t.s[4] = f2bf(a1.x); t.s[5] = f2bf(a1.y); t.s[6] = f2bf(a1.z); t.s[7] = f2bf(a1.w);
        const int kb = ks * 64 + (lane >> 4) * 16;      // byte offset in W row
#pragma unroll
        for (int n8 = 0; n8 < 8; ++n8) {
            int nr   = n8 * 16 + (lane & 15);
            int byte = (nr * 512 + kb) ^ ((nr & 7) << 4);
            bf16x8 b = *(const bf16x8*)((const char*)Wsh + byte);
            acc[n8] = __builtin_amdgcn_mfma_f32_16x16x32_bf16(t.v, b, acc[n8],
                                                              0, 0, 0);
        }
    }

    // --- epilogue: per-row amax -> int8 quantize (R10-exact) ---
    float amax[4];
#pragma unroll
    for (int r = 0; r < 4; ++r) {
        float m = 0.f;
#pragma unroll
        for (int n8 = 0; n8 < 8; ++n8) m = fmaxf(m, fabsf(acc[n8][r]));
        amax[r] = m;
    }
#pragma unroll
    for (int d = 1; d < 16; d <<= 1)
#pragma unroll
        for (int r = 0; r < 4; ++r)
            amax[r] = fmaxf(amax[r], __shfl_xor(amax[r], d));

#pragma unroll
    for (int r = 0; r < 4; ++r) {
        int grow = r0 + (lane >> 4) * 4 + r;
        if (grow < NNODES) {
            float am  = amax[r];
            float inv = am > 0.f ? 127.f / am : 0.f;
            if ((lane & 15) == 0) scale[grow] = am * (1.f / 127.f);
#pragma unroll
            for (int n8 = 0; n8 < 8; ++n8) {
                float q = rintf(acc[n8][r] * inv);
                q = fminf(127.f, fmaxf(-127.f, q));
                H8[(size_t)grow * OUT_C + n8 * 16 + (lane & 15)] = (signed char)q;
            }
        }
    }
}

// ---------------------------------------------------------------------------
// rowptr[r] = lower_bound(A_rows, r)  (A_rows sorted).  r in [0, N].
// ---------------------------------------------------------------------------
__global__ __launch_bounds__(256) void build_rowptr(const int* __restrict__ rows,
                                                    int* __restrict__ rowptr) {
    int r = blockIdx.x * 256 + threadIdx.x;
    if (r > NNODES) return;
    int lo = 0, hi = NEDGES;
    while (lo < hi) {
        int mid = (lo + hi) >> 1;
        if (rows[mid] < r) lo = mid + 1; else hi = mid;
    }
    rowptr[r] = lo;
}

// ---------------------------------------------------------------------------
// SpMM (R10-exact, best measured 59.6 us): two rows per wave, software-
// pipelined; 16 lanes/edge uint2 gathers; 64-edge shfl preload; wave-uniform
// guards; signed-int8 unpack; NT out stores.
// ---------------------------------------------------------------------------
static __device__ __forceinline__ void edge4(float acc[8], int ec, float ev,
                                             int jg, const uint2* __restrict__ H2,
                                             int cg) {
    int   c = __shfl(ec, jg);
    float v = __shfl(ev, jg);
    uint2 u = H2[(size_t)c * 16 + cg];
    acc[0] += v * (float)(signed char)(u.x);
    acc[1] += v * (float)(signed char)(u.x >> 8);
    acc[2] += v * (float)(signed char)(u.x >> 16);
    acc[3] += v * (float)(signed char)(u.x >> 24);
    acc[4] += v * (float)(signed char)(u.y);
    acc[5] += v * (float)(signed char)(u.y >> 8);
    acc[6] += v * (float)(signed char)(u.y >> 16);
    acc[7] += v * (float)(signed char)(u.y >> 24);
}

__global__ __launch_bounds__(256) void spmm_rows(const uint2* __restrict__ H2,
                                                 const int* __restrict__ rowptr,
                                                 const int* __restrict__ cols,
                                                 const float* __restrict__ vals,
                                                 const float* __restrict__ scale,
                                                 float* __restrict__ out) {
    const int wid  = threadIdx.x >> 6;
    const int lane = threadIdx.x & 63;
    const int g    = lane >> 4;      // edge subgroup 0..3
    const int cg   = lane & 15;      // channel group: channels cg*8 .. cg*8+7

    const int rowA = (blockIdx.x * 4 + wid) * 2;   // rowB = rowA + 1
    const int sA = rowptr[rowA];
    const int eA = rowptr[rowA + 1];
    const int eB = rowptr[rowA + 2];

    float accA[8], accB[8];
#pragma unroll
    for (int t = 0; t < 8; ++t) { accA[t] = 0.f; accB[t] = 0.f; }

    int baseA = sA, baseB = eA;
    while (baseA < eA || baseB < eB) {
        int cntA = eA - baseA; cntA = cntA < 0 ? 0 : (cntA > 64 ? 64 : cntA);
        int cntB = eB - baseB; cntB = cntB < 0 ? 0 : (cntB > 64 ? 64 : cntB);

        int   ecA = 0, ecB = 0;
        float evA = 0.f, evB = 0.f;
        if (lane < cntA) { ecA = cols[baseA + lane]; evA = vals[baseA + lane] * scale[ecA]; }
        if (lane < cntB) { ecB = cols[baseB + lane]; evB = vals[baseB + lane] * scale[ecB]; }

        const int mx = cntA > cntB ? cntA : cntB;
        for (int j = 0; j < mx; j += 8) {
            if (j < cntA)     edge4(accA, ecA, evA, j + g,     H2, cg);
            if (j < cntB)     edge4(accB, ecB, evB, j + g,     H2, cg);
            if (j + 4 < cntA) edge4(accA, ecA, evA, j + 4 + g, H2, cg);
            if (j + 4 < cntB) edge4(accB, ecB, evB, j + 4 + g, H2, cg);
        }

        baseA += cntA;
        baseB += cntB;
    }

    // reduce across the 4 edge subgroups
#pragma unroll
    for (int t = 0; t < 8; ++t) {
        accA[t] += __shfl_xor(accA[t], 16);
        accA[t] += __shfl_xor(accA[t], 32);
        accB[t] += __shfl_xor(accB[t], 16);
        accB[t] += __shfl_xor(accB[t], 32);
    }
    if (lane < 16) {
        f32x4 a0 = { accA[0], accA[1], accA[2], accA[3] };
        f32x4 a1 = { accA[4], accA[5], accA[6], accA[7] };
        f32x4 b0 = { accB[0], accB[1], accB[2], accB[3] };
        f32x4 b1 = { accB[4], accB[5], accB[6], accB[7] };
        __builtin_nontemporal_store(a0, (f32x4*)(out + (size_t)rowA * OUT_C + cg * 8));
        __builtin_nontemporal_store(a1, (f32x4*)(out + (size_t)rowA * OUT_C + cg * 8 + 4));
        __builtin_nontemporal_store(b0, (f32x4*)(out + (size_t)(rowA + 1) * OUT_C + cg * 8));
        __builtin_nontemporal_store(b1, (f32x4*)(out + (size_t)(rowA + 1) * OUT_C + cg * 8 + 4));
    }
}

// ---------------------------------------------------------------------------
extern "C" void kernel_launch(void* const* d_in, const int* in_sizes, int n_in,
                              void* d_out, int out_size, void* d_ws, size_t ws_size,
                              hipStream_t stream) {
    const float* X      = (const float*)d_in[0];
    const float* W      = (const float*)d_in[1];
    const int*   A_rows = (const int*)d_in[2];
    const int*   A_cols = (const int*)d_in[3];
    const float* A_vals = (const float*)d_in[4];
    float* out = (float*)d_out;

    signed char*    H8     = (signed char*)d_ws;                              // 12.8 MB
    float*          scale  = (float*)((char*)d_ws + (size_t)NNODES * OUT_C);  // 400 KB
    int*            rowptr = (int*)((char*)scale + (size_t)NNODES * sizeof(float));
    unsigned short* Wbf    = (unsigned short*)((char*)rowptr +
                                               (size_t)(NNODES + 2) * sizeof(int));

    wprep<<<32, 256, 0, stream>>>(W, Wbf);
    gemm_xwt<<<(NNODES + 127) / 128, 512, 0, stream>>>(X, Wbf, H8, scale);
    build_rowptr<<<(NNODES + 1 + 255) / 256, 256, 0, stream>>>(A_rows, rowptr);
    spmm_rows<<<(NNODES + 7) / 8, 256, 0, stream>>>((const uint2*)H8, rowptr,
                                                    A_cols, A_vals, scale, out);
}